// Round 4
// baseline (1159.969 us; speedup 1.0000x reference)
//
#include <hip/hip_runtime.h>
#include <hip/hip_bf16.h>
#include <stdint.h>

#define B_ 4
#define L_ 4096
#define D_ 2048
#define TD_ (3 * D_)          // 6144
#define CHUNKS 128
#define CLEN (L_ / CHUNKS)    // 32
#define M_ (B_ * L_)          // 16384
#define K_ 2048
#define NT (K_ / 64)          // 32 K-tiles

typedef __bf16 bf16x8 __attribute__((ext_vector_type(8)));
typedef float f32x4 __attribute__((ext_vector_type(4)));
typedef ushort u16x8 __attribute__((ext_vector_type(8)));

__device__ __forceinline__ ushort f2bf(float f) {
  uint32_t u = __builtin_bit_cast(uint32_t, f);
  u += 0x7fffu + ((u >> 16) & 1u);   // RTNE
  return (ushort)(u >> 16);
}

__device__ __forceinline__ float bf2f(ushort u) {
  return __builtin_bit_cast(float, (uint32_t)u << 16);
}

__device__ __forceinline__ float phi_f(float x) {
  return x > 0.f ? x + 1.f : __expf(x);   // elu(x)+1
}

__device__ __forceinline__ void gload_lds16(const ushort* g, ushort* l) {
  __builtin_amdgcn_global_load_lds(
      (__attribute__((address_space(1))) void*)(g),
      (__attribute__((address_space(3))) void*)(l), 16, 0, 0);
}

#define SBAR() __builtin_amdgcn_s_barrier()
#define SCHED0() __builtin_amdgcn_sched_barrier(0)
#define MFMA16(a, b, c) __builtin_amdgcn_mfma_f32_16x16x32_bf16((a), (b), (c), 0, 0, 0)

// ---------------- f32 -> bf16 conversion ----------------
__global__ void cvt_bf16_kernel(const float* __restrict__ in,
                                ushort* __restrict__ out, int n4) {
  int i = blockIdx.x * blockDim.x + threadIdx.x;
  if (i >= n4) return;
  float4 v = reinterpret_cast<const float4*>(in)[i];
  ushort4 o;
  o.x = f2bf(v.x); o.y = f2bf(v.y); o.z = f2bf(v.z); o.w = f2bf(v.w);
  reinterpret_cast<ushort4*>(out)[i] = o;
}

// ---------------- 256x256 pipelined GEMM core ----------------
// Stage one 128-row x 64-col bf16 half-tile (16 KiB) via global_load_lds,
// row-XOR swizzle applied on the GLOBAL source (LDS dest stays linear).
__device__ __forceinline__ void stage_half(const ushort* __restrict__ G,
                                           int row0, int k0, char* lds_half,
                                           int tid) {
#pragma unroll
  for (int lp = 0; lp < 2; ++lp) {
    const int p = lp * 8192 + tid * 16;        // byte offset in half-tile
    const int row = p >> 7;                    // 0..127
    const int cb = (p & 127) ^ ((row & 7) << 4);
    gload_lds16(G + (size_t)(row0 + row) * K_ + k0 + (cb >> 1),
                (ushort*)(lds_half + p));
  }
}

#define RD(p, off) (*reinterpret_cast<const bf16x8*>((p) + (off)))

// One K-tile = 4 phases, read-ahead-by-one-phase pipeline.
// c = LDS buffer parity (literal 0/1), o = 1-c.
// quadrants: q1 afL*bfrL(c)  q2 afL*bfrH  q3 afH*bfrH  q4 afH*bfrL(c)
// reads issued: ph1 -> bfrH(this tile); ph2 -> afH(this tile);
//               ph3 -> none; ph4 -> afL + bfrL(o) (next tile).
// staging: ph1/ph2 -> A(t+1) into other buf; ph3/ph4 -> B(t+2) into cur buf.
#define KTILE(t, c, o)                                                         \
  {                                                                            \
    /* ---- ph1 */                                                             \
    _Pragma("unroll") for (int j = 0; j < 2; ++j) {                            \
      bfrH[j][0] = RD(pB##c##0, 4096 + j * 2048);                              \
      bfrH[j][1] = RD(pB##c##1, 4096 + j * 2048);                              \
    }                                                                          \
    if ((t) + 1 < NT) stage_half(A, rA, (t) * 64 + 64, lsA##o, tid);           \
    SCHED0(); SBAR();                                                          \
    __builtin_amdgcn_s_setprio(1);                                             \
    _Pragma("unroll") for (int i = 0; i < 4; ++i)                              \
    _Pragma("unroll") for (int j = 0; j < 2; ++j)                              \
    _Pragma("unroll") for (int ks = 0; ks < 2; ++ks)                           \
        acc[i][j] = MFMA16(afL[i][ks], bfrL##c[j][ks], acc[i][j]);             \
    __builtin_amdgcn_s_setprio(0); SBAR();                                     \
    /* ---- ph2 */                                                             \
    _Pragma("unroll") for (int i = 0; i < 4; ++i) {                            \
      afH[i][0] = RD(pA##c##0, 8192 + i * 2048);                               \
      afH[i][1] = RD(pA##c##1, 8192 + i * 2048);                               \
    }                                                                          \
    if ((t) + 1 < NT) stage_half(A, rA + 128, (t) * 64 + 64,                   \
                                 lsA##o + 16384, tid);                         \
    SCHED0(); SBAR();                                                          \
    __builtin_amdgcn_s_setprio(1);                                             \
    _Pragma("unroll") for (int i = 0; i < 4; ++i)                              \
    _Pragma("unroll") for (int j = 0; j < 2; ++j)                              \
    _Pragma("unroll") for (int ks = 0; ks < 2; ++ks)                           \
        acc[i][2 + j] = MFMA16(afL[i][ks], bfrH[j][ks], acc[i][2 + j]);        \
    __builtin_amdgcn_s_setprio(0); SBAR();                                     \
    /* ---- ph3 */                                                             \
    if ((t) + 2 < NT) stage_half(Bm, rB, (t) * 64 + 128, lsB##c, tid);         \
    SCHED0(); SBAR();                                                          \
    __builtin_amdgcn_s_setprio(1);                                             \
    _Pragma("unroll") for (int i = 0; i < 4; ++i)                              \
    _Pragma("unroll") for (int j = 0; j < 2; ++j)                              \
    _Pragma("unroll") for (int ks = 0; ks < 2; ++ks)                           \
        acc[4 + i][2 + j] = MFMA16(afH[i][ks], bfrH[j][ks], acc[4 + i][2 + j]);\
    __builtin_amdgcn_s_setprio(0); SBAR();                                     \
    /* ---- ph4 */                                                             \
    if ((t) + 2 < NT) {                                                        \
      stage_half(Bm, rB + 128, (t) * 64 + 128, lsB##c + 16384, tid);           \
      SCHED0();                                                                \
      asm volatile("s_waitcnt vmcnt(4)" ::: "memory");                         \
    } else {                                                                   \
      SCHED0();                                                                \
      asm volatile("s_waitcnt vmcnt(0)" ::: "memory");                         \
    }                                                                          \
    if ((t) + 1 < NT) {                                                        \
      _Pragma("unroll") for (int i = 0; i < 4; ++i) {                          \
        afL[i][0] = RD(pA##o##0, i * 2048);                                    \
        afL[i][1] = RD(pA##o##1, i * 2048);                                    \
      }                                                                        \
      _Pragma("unroll") for (int j = 0; j < 2; ++j) {                          \
        bfrL##o[j][0] = RD(pB##o##0, j * 2048);                                \
        bfrL##o[j][1] = RD(pB##o##1, j * 2048);                                \
      }                                                                        \
    }                                                                          \
    SCHED0(); SBAR();                                                          \
    __builtin_amdgcn_s_setprio(1);                                             \
    _Pragma("unroll") for (int i = 0; i < 4; ++i)                              \
    _Pragma("unroll") for (int j = 0; j < 2; ++j)                              \
    _Pragma("unroll") for (int ks = 0; ks < 2; ++ks)                           \
        acc[4 + i][j] = MFMA16(afH[i][ks], bfrL##c[j][ks], acc[4 + i][j]);     \
    __builtin_amdgcn_s_setprio(0); SBAR();                                     \
  }

__device__ __forceinline__ void gemm_core(const ushort* __restrict__ A,
                                          const ushort* __restrict__ Bm,
                                          int bm, int bn, char* ls,
                                          f32x4 (&acc)[8][4]) {
  const int tid = threadIdx.x;
  const int lane = tid & 63, wid = tid >> 6;
  const int wm = (wid >> 2) * 128, wn = (wid & 3) * 64;
  const int l16 = lane & 15, kg = lane >> 4;
  const int rA = bm * 256, rB = bn * 256;

  char* lsA0 = ls;            // buf0 A tile, 32 KiB
  char* lsA1 = ls + 32768;    // buf1 A
  char* lsB0 = ls + 65536;    // buf0 B
  char* lsB1 = ls + 98304;    // buf1 B

  // Hoisted swizzled fragment base pointers: frag(row, ks) lives at
  // base + i*2048 (+8192 for hi) with base = tile + (w + l16)*128 + aoff[ks],
  // aoff[ks] = 16*((ks*4+kg) ^ (l16&7)).
  const int v7 = l16 & 7;
  const int aoff0 = 16 * (kg ^ v7);
  const int aoff1 = 16 * ((4 + kg) ^ v7);
  const char* pA00 = lsA0 + (wm + l16) * 128 + aoff0;
  const char* pA01 = lsA0 + (wm + l16) * 128 + aoff1;
  const char* pA10 = lsA1 + (wm + l16) * 128 + aoff0;
  const char* pA11 = lsA1 + (wm + l16) * 128 + aoff1;
  const char* pB00 = lsB0 + (wn + l16) * 128 + aoff0;
  const char* pB01 = lsB0 + (wn + l16) * 128 + aoff1;
  const char* pB10 = lsB1 + (wn + l16) * 128 + aoff0;
  const char* pB11 = lsB1 + (wn + l16) * 128 + aoff1;

  // Prologue: (0).A, (0).B, (1).B; vmcnt(4) -> (0) fully landed.
  stage_half(A, rA, 0, lsA0, tid);
  stage_half(A, rA + 128, 0, lsA0 + 16384, tid);
  stage_half(Bm, rB, 0, lsB0, tid);
  stage_half(Bm, rB + 128, 0, lsB0 + 16384, tid);
  stage_half(Bm, rB, 64, lsB1, tid);
  stage_half(Bm, rB + 128, 64, lsB1 + 16384, tid);
  asm volatile("s_waitcnt vmcnt(4)" ::: "memory");
  SBAR();

  bf16x8 afL[4][2], afH[4][2], bfrH[2][2], bfrL0[2][2], bfrL1[2][2];
  // pre-issue first tile's q1 fragments
#pragma unroll
  for (int i = 0; i < 4; ++i) {
    afL[i][0] = RD(pA00, i * 2048);
    afL[i][1] = RD(pA01, i * 2048);
  }
#pragma unroll
  for (int j = 0; j < 2; ++j) {
    bfrL0[j][0] = RD(pB00, j * 2048);
    bfrL0[j][1] = RD(pB01, j * 2048);
  }

#pragma unroll 1
  for (int t2 = 0; t2 < NT; t2 += 2) {
    KTILE(t2, 0, 1);
    KTILE(t2 + 1, 1, 0);
  }
}

// XCD-chunked block remap: per XCD, 4 consecutive bm panels (A = 4 MB, L2-fit)
// sweep all bn (B panel L3-resident).
__device__ __forceinline__ void remap(int wg, int BN_TILES, int* bm, int* bn) {
  const int xcd = wg & 7;
  const int idx = wg >> 3;
  const int bi = idx & 3;
  const int t = idx >> 2;
  *bn = t % BN_TILES;
  *bm = xcd * 8 + (t / BN_TILES) * 4 + bi;
}

// ---------------- GEMM1: qkv = x @ Wqkv^T, bf16 out split q/k/v ----------------
__global__ __launch_bounds__(512, 2) void gemm_qkv8(
    const ushort* __restrict__ A, const ushort* __restrict__ Bm,
    ushort* __restrict__ qb, ushort* __restrict__ kb, ushort* __restrict__ vb) {
  extern __shared__ char ls[];
  int bm, bn;
  remap(blockIdx.x, TD_ / 256, &bm, &bn);     // 1536 blocks: 64 bm x 24 bn

  f32x4 acc[8][4] = {};
  gemm_core(A, Bm, bm, bn, ls, acc);

  const int seg = bn >> 3;                      // 0=q 1=k 2=v (8 tiles each)
  ushort* dst = seg == 0 ? qb : (seg == 1 ? kb : vb);
  const int colbase = bn * 256 - seg * 2048;
  const int tid = threadIdx.x;
  const int lane = tid & 63, wid = tid >> 6;
  const int wm = (wid >> 2) * 128, wn = (wid & 3) * 64;
  const int l16 = lane & 15, kg = lane >> 4;
#pragma unroll
  for (int i = 0; i < 8; ++i) {
    const int row0 = bm * 256 + wm + i * 16 + kg * 4;
#pragma unroll
    for (int j = 0; j < 4; ++j) {
      const int col = colbase + wn + j * 16 + l16;
      ushort* cp = dst + (size_t)row0 * D_ + col;
#pragma unroll
      for (int r = 0; r < 4; ++r) cp[(size_t)r * D_] = f2bf(acc[i][j][r]);
    }
  }
}

// ---------------- GEMM2: out = (attn @ Wout^T) * scale, f32 out ----------------
__global__ __launch_bounds__(512, 2) void gemm_out8(
    const ushort* __restrict__ A, const ushort* __restrict__ Bm,
    float* __restrict__ C, float scale) {
  extern __shared__ char ls[];
  int bm, bn;
  remap(blockIdx.x, D_ / 256, &bm, &bn);      // 512 blocks: 64 bm x 8 bn

  f32x4 acc[8][4] = {};
  gemm_core(A, Bm, bm, bn, ls, acc);

  const int tid = threadIdx.x;
  const int lane = tid & 63, wid = tid >> 6;
  const int wm = (wid >> 2) * 128, wn = (wid & 3) * 64;
  const int l16 = lane & 15, kg = lane >> 4;
#pragma unroll
  for (int i = 0; i < 8; ++i) {
    const int row0 = bm * 256 + wm + i * 16 + kg * 4;
#pragma unroll
    for (int j = 0; j < 4; ++j) {
      const int col = bn * 256 + wn + j * 16 + l16;
      float* cp = C + (size_t)row0 * D_ + col;
#pragma unroll
      for (int r = 0; r < 4; ++r) cp[(size_t)r * D_] = acc[i][j][r] * scale;
    }
  }
}

// ---------------- scan pass A: per-chunk sums of phi(k) and phi(k)*v ----------------
__global__ void chunk_sums_kernel(const ushort* __restrict__ kb,
                                  const ushort* __restrict__ vb,
                                  float* __restrict__ sums) {
  const int d0 = threadIdx.x * 8;
  const int b = blockIdx.y, c = blockIdx.z;
  float sk[8] = {}, skv[8] = {};
  const size_t rowbase = (size_t)b * L_ + (size_t)c * CLEN;
  for (int l = 0; l < CLEN; ++l) {
    const size_t idx = (rowbase + l) * D_ + d0;
    u16x8 k8 = *reinterpret_cast<const u16x8*>(kb + idx);
    u16x8 v8 = *reinterpret_cast<const u16x8*>(vb + idx);
#pragma unroll
    for (int j = 0; j < 8; ++j) {
      float k = phi_f(bf2f(k8[j]));
      sk[j] += k;
      skv[j] = fmaf(k, bf2f(v8[j]), skv[j]);
    }
  }
  float* s = sums + ((size_t)(b * CHUNKS + c) * 2) * D_ + d0;
#pragma unroll
  for (int j = 0; j < 8; ++j) {
    s[j] = sk[j];
    s[D_ + j] = skv[j];
  }
}

// ---------------- scan pass B: exclusive prefix over chunks ----------------
__global__ void chunk_prefix_kernel(float* __restrict__ sums) {
  const int idx = blockIdx.x * 256 + threadIdx.x;  // b*D + d
  const int b = idx >> 11, d = idx & (D_ - 1);
  float rk = 0.f, rkv = 0.f;
  for (int c = 0; c < CHUNKS; ++c) {
    float* s = sums + ((size_t)(b * CHUNKS + c) * 2) * D_ + d;
    float sk = s[0], skv = s[D_];
    s[0] = rk;
    s[D_] = rkv;
    rk += sk;
    rkv += skv;
  }
}

// ---------------- scan pass C: cumsum + out = q*kv/(q*k+eps) ----------------
__global__ void apply_kernel(const ushort* __restrict__ qb,
                             const ushort* __restrict__ kb,
                             const ushort* __restrict__ vb,
                             const float* __restrict__ sums,
                             ushort* __restrict__ outb) {
  const int d0 = threadIdx.x * 8;
  const int b = blockIdx.y, c = blockIdx.z;
  const float* s = sums + ((size_t)(b * CHUNKS + c) * 2) * D_ + d0;
  float rk[8], rkv[8];
#pragma unroll
  for (int j = 0; j < 8; ++j) {
    rk[j] = s[j];
    rkv[j] = s[D_ + j];
  }
  const size_t rowbase = (size_t)b * L_ + (size_t)c * CLEN;
  for (int l = 0; l < CLEN; ++l) {
    const size_t idx = (rowbase + l) * D_ + d0;
    u16x8 q8 = *reinterpret_cast<const u16x8*>(qb + idx);
    u16x8 k8 = *reinterpret_cast<const u16x8*>(kb + idx);
    u16x8 v8 = *reinterpret_cast<const u16x8*>(vb + idx);
    u16x8 o8;
#pragma unroll
    for (int j = 0; j < 8; ++j) {
      float q = phi_f(bf2f(q8[j]));
      float k = phi_f(bf2f(k8[j]));
      float v = bf2f(v8[j]);
      rkv[j] = fmaf(k, v, rkv[j]);
      rk[j] += k;
      float o = (q * rkv[j]) / fmaf(q, rk[j], 1e-9f);
      o8[j] = f2bf(o);
    }
    *reinterpret_cast<u16x8*>(outb + idx) = o8;
  }
}

extern "C" void kernel_launch(void* const* d_in, const int* in_sizes, int n_in,
                              void* d_out, int out_size, void* d_ws, size_t ws_size,
                              hipStream_t stream) {
  (void)in_sizes; (void)n_in; (void)out_size; (void)ws_size;
  const float* x = (const float*)d_in[0];
  const float* Wqkv = (const float*)d_in[1];
  const float* Wout = (const float*)d_in[2];
  float* out = (float*)d_out;

  // k,v (bf16) live inside d_out; dead before GEMM2 overwrites d_out.
  ushort* kb = (ushort*)d_out;
  ushort* vb = kb + (size_t)M_ * D_;

  char* ws = (char*)d_ws;
  size_t off = 0;
  auto alloc = [&](size_t bytes) -> void* {
    off = (off + 255) & ~(size_t)255;
    void* p = ws + off;
    off += bytes;
    return p;
  };
  ushort* qb = (ushort*)alloc((size_t)M_ * D_ * 2);               // 64 MB
  ushort* xb = (ushort*)alloc((size_t)M_ * D_ * 2);               // 64 MB
  ushort* wqb = (ushort*)alloc((size_t)TD_ * D_ * 2);             // 24 MB
  ushort* wob = (ushort*)alloc((size_t)D_ * D_ * 2);              // 8 MB
  float* sums = (float*)alloc((size_t)B_ * CHUNKS * 2 * D_ * 4);  // 8 MB
  ushort* outb = xb;  // alias: xb dead after GEMM1

  (void)hipFuncSetAttribute((const void*)gemm_qkv8,
                            hipFuncAttributeMaxDynamicSharedMemorySize, 131072);
  (void)hipFuncSetAttribute((const void*)gemm_out8,
                            hipFuncAttributeMaxDynamicSharedMemorySize, 131072);

  cvt_bf16_kernel<<<(M_ * D_ / 4 + 255) / 256, 256, 0, stream>>>(x, xb, M_ * D_ / 4);
  cvt_bf16_kernel<<<(TD_ * D_ / 4 + 255) / 256, 256, 0, stream>>>(Wqkv, wqb, TD_ * D_ / 4);
  cvt_bf16_kernel<<<(D_ * D_ / 4 + 255) / 256, 256, 0, stream>>>(Wout, wob, D_ * D_ / 4);

  gemm_qkv8<<<dim3((TD_ / 256) * (M_ / 256)), 512, 131072, stream>>>(xb, wqb, qb, kb, vb);

  chunk_sums_kernel<<<dim3(1, B_, CHUNKS), 256, 0, stream>>>(kb, vb, sums);
  chunk_prefix_kernel<<<dim3(B_ * D_ / 256), 256, 0, stream>>>(sums);
  apply_kernel<<<dim3(1, B_, CHUNKS), 256, 0, stream>>>(qb, kb, vb, sums, outb);

  gemm_out8<<<dim3((D_ / 256) * (M_ / 256)), 512, 131072, stream>>>(outb, wob, out,
                                                                    0.08838834764831845f);
}

// Round 5
// 620.171 us; speedup vs baseline: 1.8704x; 1.8704x over previous
//
#include <hip/hip_runtime.h>
#include <hip/hip_bf16.h>
#include <stdint.h>

#define B_ 4
#define L_ 4096
#define D_ 2048
#define TD_ (3 * D_)          // 6144
#define CHUNKS 128
#define CLEN (L_ / CHUNKS)    // 32
#define M_ (B_ * L_)          // 16384
#define K_ 2048
#define NT (K_ / 64)          // 32 K-tiles

typedef __bf16 bf16x8 __attribute__((ext_vector_type(8)));
typedef float f32x4 __attribute__((ext_vector_type(4)));
typedef ushort u16x8 __attribute__((ext_vector_type(8)));

__device__ __forceinline__ ushort f2bf(float f) {
  uint32_t u = __builtin_bit_cast(uint32_t, f);
  u += 0x7fffu + ((u >> 16) & 1u);   // RTNE
  return (ushort)(u >> 16);
}

__device__ __forceinline__ float bf2f(ushort u) {
  return __builtin_bit_cast(float, (uint32_t)u << 16);
}

__device__ __forceinline__ float phi_f(float x) {
  return x > 0.f ? x + 1.f : __expf(x);   // elu(x)+1
}

__device__ __forceinline__ void gload_lds16(const ushort* g, ushort* l) {
  __builtin_amdgcn_global_load_lds(
      (__attribute__((address_space(1))) void*)(g),
      (__attribute__((address_space(3))) void*)(l), 16, 0, 0);
}

#define SBAR() __builtin_amdgcn_s_barrier()
#define SCHED0() __builtin_amdgcn_sched_barrier(0)
#define LGKM0() asm volatile("s_waitcnt lgkmcnt(0)" ::: "memory")
#define MFMA16(a, b, c) __builtin_amdgcn_mfma_f32_16x16x32_bf16((a), (b), (c), 0, 0, 0)

// ---------------- f32 -> bf16 conversion ----------------
__global__ void cvt_bf16_kernel(const float* __restrict__ in,
                                ushort* __restrict__ out, int n4) {
  int i = blockIdx.x * blockDim.x + threadIdx.x;
  if (i >= n4) return;
  float4 v = reinterpret_cast<const float4*>(in)[i];
  ushort4 o;
  o.x = f2bf(v.x); o.y = f2bf(v.y); o.z = f2bf(v.z); o.w = f2bf(v.w);
  reinterpret_cast<ushort4*>(out)[i] = o;
}

// ---------------- 256x256 8-phase GEMM core ----------------
// Stage one 128-row x 64-col bf16 half-tile (16 KiB) via global_load_lds,
// row-XOR swizzle applied on the GLOBAL source (LDS dest stays linear).
__device__ __forceinline__ void stage_half(const ushort* __restrict__ G,
                                           int row0, int k0, char* lds_half,
                                           int tid) {
#pragma unroll
  for (int lp = 0; lp < 2; ++lp) {
    const int p = lp * 8192 + tid * 16;        // byte offset in half-tile
    const int row = p >> 7;                    // 0..127
    const int cb = (p & 127) ^ ((row & 7) << 4);
    gload_lds16(G + (size_t)(row0 + row) * K_ + k0 + (cb >> 1),
                (ushort*)(lds_half + p));
  }
}

#define RD(p, off) (*reinterpret_cast<const bf16x8*>((p) + (off)))

// One K-tile = 4 phases, serial reads per phase (r3 schedule), hoisted
// base-pointer addressing (all read offsets are compile-time immediates).
// c = LDS buffer parity (literal 0/1), P = c*32768.
// Stagger: ph1/ph2 stage (t+1).A -> other buf; ph3/ph4 stage (t+2).B -> this
// buf. vmcnt(4) at ph4 guarantees (t+1).A/B landed before K-tile t+1 reads.
#define KTILE(t, c)                                                            \
  {                                                                            \
    const int P = (c) * 32768;                                                 \
    /* ---- ph1: A-lo rows + B cols [wn,wn+32); stage (t+1).Ah0 */             \
    _Pragma("unroll") for (int i = 0; i < 4; ++i) {                            \
      af[i][0] = RD(bA0, P + i * 2048);                                        \
      af[i][1] = RD(bA1, P + i * 2048);                                        \
    }                                                                          \
    _Pragma("unroll") for (int j = 0; j < 2; ++j) {                            \
      bfr[j][0] = RD(bB0, P + j * 2048);                                       \
      bfr[j][1] = RD(bB1, P + j * 2048);                                       \
    }                                                                          \
    if ((t) + 1 < NT) stage_half(A, rA, (t) * 64 + 64, lsA + (P ^ 32768), tid);\
    SCHED0(); SBAR(); LGKM0(); SCHED0();                                       \
    __builtin_amdgcn_s_setprio(1);                                             \
    _Pragma("unroll") for (int i = 0; i < 4; ++i)                              \
    _Pragma("unroll") for (int j = 0; j < 2; ++j)                              \
    _Pragma("unroll") for (int ks = 0; ks < 2; ++ks)                           \
        acc[i][j] = MFMA16(af[i][ks], bfr[j][ks], acc[i][j]);                  \
    __builtin_amdgcn_s_setprio(0); SBAR();                                     \
    /* ---- ph2: B cols [wn+32,wn+64); stage (t+1).Ah1 */                      \
    _Pragma("unroll") for (int j = 2; j < 4; ++j) {                            \
      bfr[j][0] = RD(bB0, P + j * 2048);                                       \
      bfr[j][1] = RD(bB1, P + j * 2048);                                       \
    }                                                                          \
    if ((t) + 1 < NT)                                                          \
      stage_half(A, rA + 128, (t) * 64 + 64, lsA + (P ^ 32768) + 16384, tid);  \
    SCHED0(); SBAR(); LGKM0(); SCHED0();                                       \
    __builtin_amdgcn_s_setprio(1);                                             \
    _Pragma("unroll") for (int i = 0; i < 4; ++i)                              \
    _Pragma("unroll") for (int j = 2; j < 4; ++j)                              \
    _Pragma("unroll") for (int ks = 0; ks < 2; ++ks)                           \
        acc[i][j] = MFMA16(af[i][ks], bfr[j][ks], acc[i][j]);                  \
    __builtin_amdgcn_s_setprio(0); SBAR();                                     \
    /* ---- ph3: A-hi rows (reuse af regs); stage (t+2).Bh0 */                 \
    _Pragma("unroll") for (int i = 0; i < 4; ++i) {                            \
      af[i][0] = RD(bA0, P + 8192 + i * 2048);                                 \
      af[i][1] = RD(bA1, P + 8192 + i * 2048);                                 \
    }                                                                          \
    if ((t) + 2 < NT) stage_half(Bm, rB, (t) * 64 + 128, lsB + P, tid);        \
    SCHED0(); SBAR(); LGKM0(); SCHED0();                                       \
    __builtin_amdgcn_s_setprio(1);                                             \
    _Pragma("unroll") for (int i = 0; i < 4; ++i)                              \
    _Pragma("unroll") for (int j = 2; j < 4; ++j)                              \
    _Pragma("unroll") for (int ks = 0; ks < 2; ++ks)                           \
        acc[4 + i][j] = MFMA16(af[i][ks], bfr[j][ks], acc[4 + i][j]);          \
    __builtin_amdgcn_s_setprio(0); SBAR();                                     \
    /* ---- ph4: stage (t+2).Bh1; counted vmcnt; last quadrant */              \
    if ((t) + 2 < NT) {                                                        \
      stage_half(Bm, rB + 128, (t) * 64 + 128, lsB + P + 16384, tid);          \
      SCHED0();                                                                \
      asm volatile("s_waitcnt vmcnt(4)" ::: "memory");                         \
    } else {                                                                   \
      SCHED0();                                                                \
      asm volatile("s_waitcnt vmcnt(0)" ::: "memory");                         \
    }                                                                          \
    SBAR();                                                                    \
    __builtin_amdgcn_s_setprio(1);                                             \
    _Pragma("unroll") for (int i = 0; i < 4; ++i)                              \
    _Pragma("unroll") for (int j = 0; j < 2; ++j)                              \
    _Pragma("unroll") for (int ks = 0; ks < 2; ++ks)                           \
        acc[4 + i][j] = MFMA16(af[i][ks], bfr[j][ks], acc[4 + i][j]);          \
    __builtin_amdgcn_s_setprio(0); SBAR();                                     \
  }

__device__ __forceinline__ void gemm_core(const ushort* __restrict__ A,
                                          const ushort* __restrict__ Bm,
                                          int bm, int bn, char* ls,
                                          f32x4 (&acc)[8][4]) {
  const int tid = threadIdx.x;
  const int lane = tid & 63, wid = tid >> 6;
  const int wm = (wid >> 2) * 128, wn = (wid & 3) * 64;
  const int l16 = lane & 15, kg = lane >> 4;
  const int rA = bm * 256, rB = bn * 256;

  char* lsA = ls;             // A tiles: buf0 @0, buf1 @32768 (32 KiB each)
  char* lsB = ls + 65536;     // B tiles: buf0 @0, buf1 @32768

  // Hoisted swizzled addressing. For fragment row = w + i*16 + l16 the
  // swizzle XOR uses row&7 == l16&7 (w, i*16 are multiples of 8/16), so:
  //   addr = base + (w+l16)*128 + P + i*2048 (+8192 hi-half) + cks
  //   cks  = (ks*64 + kg*16) ^ ((l16&7)<<4)   -- per-thread constant
  const int v16 = (l16 & 7) << 4;
  const int c0 = (kg * 16) ^ v16;
  const int c1 = (64 + kg * 16) ^ v16;
  const char* bA0 = lsA + (wm + l16) * 128 + c0;
  const char* bA1 = lsA + (wm + l16) * 128 + c1;
  const char* bB0 = lsB + (wn + l16) * 128 + c0;
  const char* bB1 = lsB + (wn + l16) * 128 + c1;

  // Prologue: (0).A, (0).B, (1).B; vmcnt(4) -> (0) fully landed.
  stage_half(A, rA, 0, lsA, tid);
  stage_half(A, rA + 128, 0, lsA + 16384, tid);
  stage_half(Bm, rB, 0, lsB, tid);
  stage_half(Bm, rB + 128, 0, lsB + 16384, tid);
  stage_half(Bm, rB, 64, lsB + 32768, tid);
  stage_half(Bm, rB + 128, 64, lsB + 32768 + 16384, tid);
  asm volatile("s_waitcnt vmcnt(4)" ::: "memory");
  SBAR();

  bf16x8 af[4][2], bfr[4][2];
#pragma unroll 1
  for (int t2 = 0; t2 < NT; t2 += 2) {
    KTILE(t2, 0);
    KTILE(t2 + 1, 1);
  }
}

// ---------------- GEMM1: qkv = x @ Wqkv^T, bf16 out split q/k/v ----------------
__global__ __launch_bounds__(512, 2) void gemm_qkv8(
    const ushort* __restrict__ A, const ushort* __restrict__ Bm,
    ushort* __restrict__ qb, ushort* __restrict__ kb, ushort* __restrict__ vb) {
  extern __shared__ char ls[];
  const int nwg = gridDim.x;                    // 1536, %8==0
  const int wg = blockIdx.x;
  const int swz = (wg & 7) * (nwg >> 3) + (wg >> 3);
  const int MT = M_ / 256;                      // 64
  const int bm = swz % MT, bn = swz / MT;       // bn in [0,24)

  f32x4 acc[8][4] = {};
  gemm_core(A, Bm, bm, bn, ls, acc);

  const int seg = bn >> 3;                      // 0=q 1=k 2=v (8 tiles each)
  ushort* dst = seg == 0 ? qb : (seg == 1 ? kb : vb);
  const int colbase = bn * 256 - seg * 2048;
  const int tid = threadIdx.x;
  const int lane = tid & 63, wid = tid >> 6;
  const int wm = (wid >> 2) * 128, wn = (wid & 3) * 64;
  const int l16 = lane & 15, kg = lane >> 4;
#pragma unroll
  for (int i = 0; i < 8; ++i) {
    const int row0 = bm * 256 + wm + i * 16 + kg * 4;
#pragma unroll
    for (int j = 0; j < 4; ++j) {
      const int col = colbase + wn + j * 16 + l16;
      ushort* cp = dst + (size_t)row0 * D_ + col;
#pragma unroll
      for (int r = 0; r < 4; ++r) cp[(size_t)r * D_] = f2bf(acc[i][j][r]);
    }
  }
}

// ---------------- GEMM2: out = (attn @ Wout^T) * scale, f32 out ----------------
__global__ __launch_bounds__(512, 2) void gemm_out8(
    const ushort* __restrict__ A, const ushort* __restrict__ Bm,
    float* __restrict__ C, float scale) {
  extern __shared__ char ls[];
  const int nwg = gridDim.x;                    // 512, %8==0
  const int wg = blockIdx.x;
  const int swz = (wg & 7) * (nwg >> 3) + (wg >> 3);
  const int MT = M_ / 256;
  const int bm = swz % MT, bn = swz / MT;       // bn in [0,8)

  f32x4 acc[8][4] = {};
  gemm_core(A, Bm, bm, bn, ls, acc);

  const int tid = threadIdx.x;
  const int lane = tid & 63, wid = tid >> 6;
  const int wm = (wid >> 2) * 128, wn = (wid & 3) * 64;
  const int l16 = lane & 15, kg = lane >> 4;
#pragma unroll
  for (int i = 0; i < 8; ++i) {
    const int row0 = bm * 256 + wm + i * 16 + kg * 4;
#pragma unroll
    for (int j = 0; j < 4; ++j) {
      const int col = bn * 256 + wn + j * 16 + l16;
      float* cp = C + (size_t)row0 * D_ + col;
#pragma unroll
      for (int r = 0; r < 4; ++r) cp[(size_t)r * D_] = acc[i][j][r] * scale;
    }
  }
}

// ---------------- scan pass A: per-chunk sums of phi(k) and phi(k)*v ----------------
__global__ void chunk_sums_kernel(const ushort* __restrict__ kb,
                                  const ushort* __restrict__ vb,
                                  float* __restrict__ sums) {
  const int d0 = threadIdx.x * 8;
  const int b = blockIdx.y, c = blockIdx.z;
  float sk[8] = {}, skv[8] = {};
  const size_t rowbase = (size_t)b * L_ + (size_t)c * CLEN;
  for (int l = 0; l < CLEN; ++l) {
    const size_t idx = (rowbase + l) * D_ + d0;
    u16x8 k8 = *reinterpret_cast<const u16x8*>(kb + idx);
    u16x8 v8 = *reinterpret_cast<const u16x8*>(vb + idx);
#pragma unroll
    for (int j = 0; j < 8; ++j) {
      float k = phi_f(bf2f(k8[j]));
      sk[j] += k;
      skv[j] = fmaf(k, bf2f(v8[j]), skv[j]);
    }
  }
  float* s = sums + ((size_t)(b * CHUNKS + c) * 2) * D_ + d0;
#pragma unroll
  for (int j = 0; j < 8; ++j) {
    s[j] = sk[j];
    s[D_ + j] = skv[j];
  }
}

// ---------------- scan pass B: exclusive prefix over chunks ----------------
__global__ void chunk_prefix_kernel(float* __restrict__ sums) {
  const int idx = blockIdx.x * 256 + threadIdx.x;  // b*D + d
  const int b = idx >> 11, d = idx & (D_ - 1);
  float rk = 0.f, rkv = 0.f;
  for (int c = 0; c < CHUNKS; ++c) {
    float* s = sums + ((size_t)(b * CHUNKS + c) * 2) * D_ + d;
    float sk = s[0], skv = s[D_];
    s[0] = rk;
    s[D_] = rkv;
    rk += sk;
    rkv += skv;
  }
}

// ---------------- scan pass C: cumsum + out = q*kv/(q*k+eps) ----------------
__global__ void apply_kernel(const ushort* __restrict__ qb,
                             const ushort* __restrict__ kb,
                             const ushort* __restrict__ vb,
                             const float* __restrict__ sums,
                             ushort* __restrict__ outb) {
  const int d0 = threadIdx.x * 8;
  const int b = blockIdx.y, c = blockIdx.z;
  const float* s = sums + ((size_t)(b * CHUNKS + c) * 2) * D_ + d0;
  float rk[8], rkv[8];
#pragma unroll
  for (int j = 0; j < 8; ++j) {
    rk[j] = s[j];
    rkv[j] = s[D_ + j];
  }
  const size_t rowbase = (size_t)b * L_ + (size_t)c * CLEN;
  for (int l = 0; l < CLEN; ++l) {
    const size_t idx = (rowbase + l) * D_ + d0;
    u16x8 q8 = *reinterpret_cast<const u16x8*>(qb + idx);
    u16x8 k8 = *reinterpret_cast<const u16x8*>(kb + idx);
    u16x8 v8 = *reinterpret_cast<const u16x8*>(vb + idx);
    u16x8 o8;
#pragma unroll
    for (int j = 0; j < 8; ++j) {
      float q = phi_f(bf2f(q8[j]));
      float k = phi_f(bf2f(k8[j]));
      float v = bf2f(v8[j]);
      rkv[j] = fmaf(k, v, rkv[j]);
      rk[j] += k;
      float o = (q * rkv[j]) / fmaf(q, rk[j], 1e-9f);
      o8[j] = f2bf(o);
    }
    *reinterpret_cast<u16x8*>(outb + idx) = o8;
  }
}

extern "C" void kernel_launch(void* const* d_in, const int* in_sizes, int n_in,
                              void* d_out, int out_size, void* d_ws, size_t ws_size,
                              hipStream_t stream) {
  (void)in_sizes; (void)n_in; (void)out_size; (void)ws_size;
  const float* x = (const float*)d_in[0];
  const float* Wqkv = (const float*)d_in[1];
  const float* Wout = (const float*)d_in[2];
  float* out = (float*)d_out;

  // k,v (bf16) live inside d_out; dead before GEMM2 overwrites d_out.
  ushort* kb = (ushort*)d_out;
  ushort* vb = kb + (size_t)M_ * D_;

  char* ws = (char*)d_ws;
  size_t off = 0;
  auto alloc = [&](size_t bytes) -> void* {
    off = (off + 255) & ~(size_t)255;
    void* p = ws + off;
    off += bytes;
    return p;
  };
  ushort* qb = (ushort*)alloc((size_t)M_ * D_ * 2);               // 64 MB
  ushort* xb = (ushort*)alloc((size_t)M_ * D_ * 2);               // 64 MB
  ushort* wqb = (ushort*)alloc((size_t)TD_ * D_ * 2);             // 24 MB
  ushort* wob = (ushort*)alloc((size_t)D_ * D_ * 2);              // 8 MB
  float* sums = (float*)alloc((size_t)B_ * CHUNKS * 2 * D_ * 4);  // 8 MB
  ushort* outb = xb;  // alias: xb dead after GEMM1

  (void)hipFuncSetAttribute((const void*)gemm_qkv8,
                            hipFuncAttributeMaxDynamicSharedMemorySize, 131072);
  (void)hipFuncSetAttribute((const void*)gemm_out8,
                            hipFuncAttributeMaxDynamicSharedMemorySize, 131072);

  cvt_bf16_kernel<<<(M_ * D_ / 4 + 255) / 256, 256, 0, stream>>>(x, xb, M_ * D_ / 4);
  cvt_bf16_kernel<<<(TD_ * D_ / 4 + 255) / 256, 256, 0, stream>>>(Wqkv, wqb, TD_ * D_ / 4);
  cvt_bf16_kernel<<<(D_ * D_ / 4 + 255) / 256, 256, 0, stream>>>(Wout, wob, D_ * D_ / 4);

  gemm_qkv8<<<dim3((TD_ / 256) * (M_ / 256)), 512, 131072, stream>>>(xb, wqb, qb, kb, vb);

  chunk_sums_kernel<<<dim3(1, B_, CHUNKS), 256, 0, stream>>>(kb, vb, sums);
  chunk_prefix_kernel<<<dim3(B_ * D_ / 256), 256, 0, stream>>>(sums);
  apply_kernel<<<dim3(1, B_, CHUNKS), 256, 0, stream>>>(qb, kb, vb, sums, outb);

  gemm_out8<<<dim3((D_ / 256) * (M_ / 256)), 512, 131072, stream>>>(outb, wob, out,
                                                                    0.08838834764831845f);
}